// Round 17
// baseline (196.036 us; speedup 1.0000x reference)
//
#include <hip/hip_runtime.h>
#include <hip/hip_bf16.h>
#include <cstdint>

#define CIN   128
#define COUT  256
#define BATCH 16
#define HH    64
#define WW    64
#define TH    32
#define TW    32
#define NT    (BATCH*TH*TW)   /* 16384 winograd tiles */
#define APQ   (COUT*CIN)      /* U plane: 32768 elems */
#define BPQ   (NT*CIN)        /* V plane: 2097152 elems */

typedef __bf16 bf16x8 __attribute__((ext_vector_type(8)));
typedef float  f32x4  __attribute__((ext_vector_type(4)));

__device__ __forceinline__ void gload16(const void* g, void* l) {
    __builtin_amdgcn_global_load_lds(
        (const __attribute__((address_space(1))) uint32_t*)g,
        (__attribute__((address_space(3))) uint32_t*)l, 16, 0, 0);
}

// ---------------------------------------------------------------------------
// weight transform (device fn, fused into itrans kernel as extra grid.y row)
// ---------------------------------------------------------------------------
__device__ __forceinline__ void wtrans_one(const float* __restrict__ w,
                                           __hip_bfloat16* __restrict__ U,
                                           int idx) {
    const float* wp = w + idx * 9;
    float g[3][3];
#pragma unroll
    for (int x = 0; x < 3; x++)
#pragma unroll
        for (int y = 0; y < 3; y++) g[x][y] = wp[x * 3 + y];

    float t[4][3];
#pragma unroll
    for (int y = 0; y < 3; y++) {
        t[0][y] = g[0][y];
        t[1][y] = 0.5f * (g[0][y] + g[1][y] + g[2][y]);
        t[2][y] = 0.5f * (g[0][y] - g[1][y] + g[2][y]);
        t[3][y] = g[2][y];
    }
#pragma unroll
    for (int p = 0; p < 4; p++) {
        float u0 = t[p][0];
        float u1 = 0.5f * (t[p][0] + t[p][1] + t[p][2]);
        float u2 = 0.5f * (t[p][0] - t[p][1] + t[p][2]);
        float u3 = t[p][2];
        U[(p * 4 + 0) * APQ + idx] = __float2bfloat16(u0);
        U[(p * 4 + 1) * APQ + idx] = __float2bfloat16(u1);
        U[(p * 4 + 2) * APQ + idx] = __float2bfloat16(u2);
        U[(p * 4 + 3) * APQ + idx] = __float2bfloat16(u3);
    }
}

// ---------------------------------------------------------------------------
// Kernel A: input transform (full-row blocks) + fused weight transform.
// grid = (TH, BATCH+1): blocks with by==BATCH do the weight transform
// (32 blocks x 1024 thr = 32768 = COUT*CIN threads, one weight each).
// ---------------------------------------------------------------------------
__global__ __launch_bounds__(1024) void wg_itrans3(const float* __restrict__ X,
                                                   const float* __restrict__ w,
                                                   __hip_bfloat16* __restrict__ V,
                                                   __hip_bfloat16* __restrict__ U) {
    const int i = blockIdx.x;
    const int b = blockIdx.y;
    const int tid = threadIdx.x;

    if (b == BATCH) {                    // weight-transform blocks
        wtrans_one(w, U, i * 1024 + tid);
        return;
    }

    __shared__ __hip_bfloat16 Xp[128 * 266];    // ~68 KB

    // zero the x=-1 / x=64 border columns (128c * 4r * 2 = 1024 = blockDim)
    {
        int c = tid >> 3, r = (tid >> 1) & 3, e = tid & 1;
        Xp[c * 266 + r * 66 + e * 65] = __float2bfloat16(0.f);
    }
    // main load: rows y = 2i-1+r, float4-coalesced in x
#pragma unroll
    for (int it = 0; it < 8; ++it) {
        int flat = it * 4096 + tid * 4;
        int c = flat >> 8, r = (flat >> 6) & 3, x = flat & 63;
        int y = 2 * i - 1 + r;
        float4 v = make_float4(0.f, 0.f, 0.f, 0.f);
        if (y >= 0 && y < HH)
            v = *reinterpret_cast<const float4*>(&X[(((b * CIN + c) * HH + y) << 6) + x]);
        int base = c * 266 + r * 66 + 1 + x;
        Xp[base + 0] = __float2bfloat16(v.x);
        Xp[base + 1] = __float2bfloat16(v.y);
        Xp[base + 2] = __float2bfloat16(v.z);
        Xp[base + 3] = __float2bfloat16(v.w);
    }
    __syncthreads();

    const int c  = tid & 127;
    const int jj = tid >> 7;
#pragma unroll
    for (int jl = 0; jl < 4; ++jl) {
        const int j = jj * 4 + jl;
        float d[4][4];
#pragma unroll
        for (int r = 0; r < 4; r++) {
            int off = c * 266 + r * 66 + 2 * j;
            ushort2 s01 = *reinterpret_cast<const ushort2*>(&Xp[off]);
            ushort2 s23 = *reinterpret_cast<const ushort2*>(&Xp[off + 2]);
            d[r][0] = __bfloat162float(*reinterpret_cast<__hip_bfloat16*>(&s01.x));
            d[r][1] = __bfloat162float(*reinterpret_cast<__hip_bfloat16*>(&s01.y));
            d[r][2] = __bfloat162float(*reinterpret_cast<__hip_bfloat16*>(&s23.x));
            d[r][3] = __bfloat162float(*reinterpret_cast<__hip_bfloat16*>(&s23.y));
        }
        float t0[4], t1[4], t2[4], t3[4];
#pragma unroll
        for (int y = 0; y < 4; y++) {
            t0[y] = d[0][y] - d[2][y];
            t1[y] = d[1][y] + d[2][y];
            t2[y] = d[2][y] - d[1][y];
            t3[y] = d[1][y] - d[3][y];
        }
        float vm[4][4];
#pragma unroll
        for (int p = 0; p < 4; p++) {
            const float* tp = (p == 0) ? t0 : (p == 1) ? t1 : (p == 2) ? t2 : t3;
            vm[p][0] = tp[0] - tp[2];
            vm[p][1] = tp[1] + tp[2];
            vm[p][2] = tp[2] - tp[1];
            vm[p][3] = tp[1] - tp[3];
        }
        const int bij = (b << 10) + (i << 5) + j;
        const size_t vo = (size_t)bij * CIN + c;
#pragma unroll
        for (int p = 0; p < 4; p++)
#pragma unroll
            for (int q = 0; q < 4; q++)
                V[(size_t)(p * 4 + q) * BPQ + vo] = __float2bfloat16(vm[p][q]);
    }
}

// ---------------------------------------------------------------------------
// Kernel B: fused GEMM + output transform — R13 macro-structure, DE-PINNED
// body (m141 lesson: sched_barrier(0) order-pinning defeats the compiler's
// near-optimal fine-grained lgkmcnt interleave; m97 shows compiler-scheduled
// ds_read->MFMA reaches 874 TF). Kept: 4 LDS buffers, depth-3 staging,
// counted vmcnt(8) (tail 4 -> 0), two barriers/slot, XOR granule swizzle,
// per-pq register fold. Removed: all sched_barriers, manual lgkmcnt, setprio,
// cross-slot register prefetch (compiler pipelines the in-slot loads).
// Race analysis: every wave drains its own stage t+1 via vmcnt(8) before the
// slot-t top barrier => all waves' stage t+1 published at barrier-exit; slot
// t reads buf t (drained one slot earlier). Tail: vmc 8,8,...,8,4,0,none.
// ---------------------------------------------------------------------------
#define ABYTES 16384
#define BUFSZ  32768

__global__ __launch_bounds__(512, 2) void wg_gemm17(const __hip_bfloat16* __restrict__ U,
                                                    const __hip_bfloat16* __restrict__ V,
                                                    const float* __restrict__ bias,
                                                    float* __restrict__ out) {
    __shared__ char lds[4 * BUFSZ];      // 128 KB

    // bijective XCD swizzle (256 % 8 == 0): 32 consecutive wg per XCD
    int orig = blockIdx.x;
    int wgid = (orig & 7) * 32 + (orig >> 3);
    const int mt = wgid & 1, nt = wgid >> 1;
    const int m0 = mt * 128, n0 = nt * 128;

    const int tid  = threadIdx.x;
    const int lane = tid & 63;
    const int wave = tid >> 6;
    const int wm = wave >> 2, wn = wave & 3;

    // staging: chunk c holds tile granule (row R=c>>3, gran G=(c&7)^(R&7))
    const __hip_bfloat16* pa[2];
    const __hip_bfloat16* pb[2];
    int ldsA[2], ldsB[2];
#pragma unroll
    for (int ch = 0; ch < 2; ch++) {
        int c = ch * 512 + tid;
        int R = c >> 3;
        int G = (c & 7) ^ (R & 7);
        pa[ch] = U + (m0 + R) * CIN + G * 8;
        pb[ch] = V + (size_t)(n0 + R) * CIN + G * 8;
        ldsA[ch] = c * 16;
        ldsB[ch] = ABYTES + c * 16;
    }

    // ds_read offsets: row r, k-granule g -> byte r*128 + ((g ^ (r&7))<<4)
    const int la = lane & 15, hq = lane >> 4, l7 = lane & 7;
    int aoff[2], boff[2];
#pragma unroll
    for (int kk = 0; kk < 2; kk++) {
        int g = (kk * 4 + hq) ^ l7;
        aoff[kk] = (wm * 64 + la) * 128 + (g << 4);
        boff[kk] = ABYTES + (wn * 32 + la) * 128 + (g << 4);
    }

    f32x4 yac[2][2][4][2];
#pragma unroll
    for (int x = 0; x < 2; x++)
#pragma unroll
        for (int y = 0; y < 2; y++)
#pragma unroll
            for (int mi = 0; mi < 4; mi++)
#pragma unroll
                for (int nj = 0; nj < 2; nj++) yac[x][y][mi][nj] = (f32x4){0.f, 0.f, 0.f, 0.f};
    f32x4 mac[4][2];
    const f32x4 fz = (f32x4){0.f, 0.f, 0.f, 0.f};

    auto stage = [&](int s) {
        char* sb = lds + (s & 3) * BUFSZ;
        const int pq = s >> 1, kb = (s & 1) * 64;
        gload16(pa[0] + pq * APQ + kb, sb + ldsA[0]);
        gload16(pa[1] + pq * APQ + kb, sb + ldsA[1]);
        gload16(pb[0] + (size_t)pq * BPQ + kb, sb + ldsB[0]);
        gload16(pb[1] + (size_t)pq * BPQ + kb, sb + ldsB[1]);
    };

    auto fold = [&](int pq) {            // M[pq] -> Y planes, uniform weights
        const int p = pq >> 2, q = pq & 3;
        const float s1p = (p >= 2) ? -1.f : 1.f;
        const float s1q = (q >= 2) ? -1.f : 1.f;
        if (p != 3 && q != 3) {
#pragma unroll
            for (int mi = 0; mi < 4; mi++)
#pragma unroll
                for (int nj = 0; nj < 2; nj++) yac[0][0][mi][nj] += mac[mi][nj];
        }
        if (p != 3 && q != 0) {
#pragma unroll
            for (int mi = 0; mi < 4; mi++)
#pragma unroll
                for (int nj = 0; nj < 2; nj++) yac[0][1][mi][nj] += s1q * mac[mi][nj];
        }
        if (p != 0 && q != 3) {
#pragma unroll
            for (int mi = 0; mi < 4; mi++)
#pragma unroll
                for (int nj = 0; nj < 2; nj++) yac[1][0][mi][nj] += s1p * mac[mi][nj];
        }
        if (p != 0 && q != 0) {
            const float s11 = s1p * s1q;
#pragma unroll
            for (int mi = 0; mi < 4; mi++)
#pragma unroll
                for (int nj = 0; nj < 2; nj++) yac[1][1][mi][nj] += s11 * mac[mi][nj];
        }
    };

    // prologue: 3 stages in flight
    stage(0); stage(1); stage(2);

#pragma unroll
    for (int t = 0; t < 32; ++t) {
        if (t <= 28) stage(t + 3);

        // counted drain of this wave's stage t+1; barrier publishes all waves'
        if (t <= 28)      asm volatile("s_waitcnt vmcnt(8)" ::: "memory");
        else if (t == 29) asm volatile("s_waitcnt vmcnt(4)" ::: "memory");
        else if (t == 30) asm volatile("s_waitcnt vmcnt(0)" ::: "memory");
        __builtin_amdgcn_s_barrier();

        // body: compiler-scheduled (fine-grained lgkmcnt interleave, m97)
        const char* rb = lds + (t & 3) * BUFSZ;
        bf16x8 a0[4], b0[2], a1[4], b1[2];
#pragma unroll
        for (int mi = 0; mi < 4; mi++) {
            a0[mi] = *reinterpret_cast<const bf16x8*>(rb + aoff[0] + mi * 2048);
            a1[mi] = *reinterpret_cast<const bf16x8*>(rb + aoff[1] + mi * 2048);
        }
#pragma unroll
        for (int nj = 0; nj < 2; nj++) {
            b0[nj] = *reinterpret_cast<const bf16x8*>(rb + boff[0] + nj * 2048);
            b1[nj] = *reinterpret_cast<const bf16x8*>(rb + boff[1] + nj * 2048);
        }

        const bool init = (t & 1) == 0;
#pragma unroll
        for (int mi = 0; mi < 4; mi++)
#pragma unroll
            for (int nj = 0; nj < 2; nj++)
                mac[mi][nj] = __builtin_amdgcn_mfma_f32_16x16x32_bf16(
                    a0[mi], b0[nj], init ? fz : mac[mi][nj], 0, 0, 0);
#pragma unroll
        for (int mi = 0; mi < 4; mi++)
#pragma unroll
            for (int nj = 0; nj < 2; nj++)
                mac[mi][nj] = __builtin_amdgcn_mfma_f32_16x16x32_bf16(
                    a1[mi], b1[nj], mac[mi][nj], 0, 0, 0);

        if (t & 1) fold(t >> 1);         // pq complete (dataflow-ordered)

        __builtin_amdgcn_s_barrier();
    }

    // ---- writeout: D frag: col(bij)=lane&15, row(kout)=(lane>>4)*4+r ----
    const int lr = lane & 15, rg = lane >> 4;
#pragma unroll
    for (int mi = 0; mi < 4; mi++) {
#pragma unroll
        for (int r = 0; r < 4; r++) {
            const int kout = m0 + wm * 64 + mi * 16 + rg * 4 + r;
            const float bvv = bias[kout];
#pragma unroll
            for (int nj = 0; nj < 2; nj++) {
                const int bij = n0 + wn * 32 + nj * 16 + lr;
                const int bb = bij >> 10, ti = (bij >> 5) & 31, tj = bij & 31;
                float* op = out + (((size_t)bb * COUT + kout) * HH + 2 * ti) * WW + 2 * tj;
                *reinterpret_cast<float2*>(op) =
                    make_float2(yac[0][0][mi][nj][r] + bvv, yac[0][1][mi][nj][r] + bvv);
                *reinterpret_cast<float2*>(op + WW) =
                    make_float2(yac[1][0][mi][nj][r] + bvv, yac[1][1][mi][nj][r] + bvv);
            }
        }
    }
}

// ---------------------------------------------------------------------------
extern "C" void kernel_launch(void* const* d_in, const int* in_sizes, int n_in,
                              void* d_out, int out_size, void* d_ws, size_t ws_size,
                              hipStream_t stream) {
    const float* X    = (const float*)d_in[0];
    const float* w    = (const float*)d_in[1];
    const float* bias = (const float*)d_in[2];
    float* out        = (float*)d_out;

    __hip_bfloat16* U = (__hip_bfloat16*)d_ws;                       // 1 MB
    __hip_bfloat16* V = (__hip_bfloat16*)((char*)d_ws + (1u << 20)); // 64 MB

    wg_itrans3<<<dim3(TH, BATCH + 1), 1024, 0, stream>>>(X, w, V, U);
    wg_gemm17<<<(COUT / 128) * (NT / 128), 512, 0, stream>>>(U, V, bias, out);
}